// Round 9
// baseline (1343.895 us; speedup 1.0000x reference)
//
#include <hip/hip_runtime.h>
#include <math.h>

#define NN 20000
#define GG 8
#define NPG 2500
#define EE 640000
#define EPAD 944000   // upper bound: E + 15*NN, per-node degree padded to mult of 16
#define NLAYERS 3
#define CUTR 6.0f
#define AVGN 32.0f
#define NBASIS 8
#define WPL 22528     // ushorts of frag-layout weights per layer (Wr1f 2048 + Wr2f 4096 + Wr3f 16384)
#define RTS 88        // shorts per roundtrip row (16B-aligned, breaks 8-way bank conflict of 80)

typedef short bf16x8 __attribute__((ext_vector_type(8)));
typedef float f32x4 __attribute__((ext_vector_type(4)));

__device__ __forceinline__ float silu_f(float x){ return x / (1.0f + __expf(-x)); }
__device__ __forceinline__ unsigned short f2bf(float f){
  union { float f; unsigned u; } x; x.f = f;
  unsigned r = x.u + 0x7FFFu + ((x.u >> 16) & 1u);   // RNE
  return (unsigned short)(r >> 16);
}

// ---------------- CSR degree count ----------------
__global__ void k_count(const int* __restrict__ ei, int* __restrict__ deg)
{
  int e = blockIdx.x * 256 + threadIdx.x;
  if (e >= EE) return;
  atomicAdd(&deg[ei[EE + e]], 1);
}

// padded scan: each row's extent rounded up to multiple of 16 (tiles never cross nodes)
__global__ void k_scan(const int* __restrict__ deg, int* __restrict__ rowptrP,
                       int* __restrict__ cursor)
{
  __shared__ int buf[1024];
  __shared__ int carry;
  int tid = threadIdx.x;
  if (tid == 0) carry = 0;
  __syncthreads();
  for (int base = 0; base < NN; base += 1024) {
    int i = base + tid;
    int x = (i < NN) ? ((deg[i] + 15) & ~15) : 0;
    buf[tid] = x; __syncthreads();
    for (int off = 1; off < 1024; off <<= 1) {
      int t = (tid >= off) ? buf[tid - off] : 0;
      __syncthreads();
      buf[tid] += t;
      __syncthreads();
    }
    int incl = buf[tid];
    int c = carry;
    __syncthreads();
    if (i < NN) { rowptrP[i] = c + incl - x; cursor[i] = c + incl - x; }
    if (tid == 1023) carry = c + incl;
    __syncthreads();
  }
  if (tid == 0) rowptrP[NN] = carry;
}

// ---------------- scatter edge ids into padded CSR slots (perm nondeterministic) ----------------
__global__ void k_scatter(const int* __restrict__ ei, int* __restrict__ cursor,
                          unsigned* __restrict__ csrE)
{
  int e = blockIdx.x * 256 + threadIdx.x;
  if (e >= EE) return;
  int slot = atomicAdd(&cursor[ei[EE + e]], 1);
  csrE[slot] = (unsigned)e;
}

// ---------------- per-row sort by edge id -> DETERMINISTIC slot assignment ----------------
__global__ __launch_bounds__(512) void k_sortrows(const int* __restrict__ rowptrP,
                                                  unsigned* __restrict__ csrE)
{
  __shared__ unsigned buf[8*512];
  int w = threadIdx.x >> 6, lane = threadIdx.x & 63;
  unsigned* b = buf + w*512;
  int r = blockIdx.x*8 + w;
  int start = rowptrP[r], end = rowptrP[r+1];
  int P = end - start;
  if (P < 2 || P > 512) return;   // max padded degree << 512 for this input
  for (int i = lane; i < P; i += 64) b[i] = csrE[start + i];
  for (int pass = 0; pass < P; ++pass) {
    int par = pass & 1;
    for (int i = lane; 2*i + par + 1 < P; i += 64) {
      int idx = 2*i + par;
      unsigned a = b[idx], c = b[idx+1];
      if (a > c) { b[idx] = c; b[idx+1] = a; }
    }
  }
  for (int i = lane; i < P; i += 64) csrE[start + i] = b[i];
}

// ---------------- geometry per SLOT (deterministic values; pads -> zeros) ----------------
__global__ void k_geom_slot(const float* __restrict__ pos, const float* __restrict__ cell,
                            const float* __restrict__ Sij, const int* __restrict__ ei,
                            const int* __restrict__ batch, const unsigned* __restrict__ csrE,
                            unsigned short* __restrict__ efeatB, float* __restrict__ y1mP,
                            int* __restrict__ sndP)
{
  int slot = blockIdx.x * 256 + threadIdx.x;
  if (slot >= EPAD) return;
  int e = (int)csrE[slot];
  if (e < 0) {
    ((uint4*)efeatB)[slot] = make_uint4(0,0,0,0);
    ((float4*)y1mP)[slot]  = make_float4(0,0,0,0);
    sndP[slot] = 0;
    return;
  }
  int snd = ei[e], rcv = ei[EE + e];
  int g = batch[snd];
  float s0 = Sij[e*3+0], s1 = Sij[e*3+1], s2_ = Sij[e*3+2];
  const float* cg = cell + g*9;
  float R[3];
  #pragma unroll
  for (int j = 0; j < 3; ++j) {
    float shift = s0*cg[0*3+j] + s1*cg[1*3+j] + s2_*cg[2*3+j];
    R[j] = (pos[rcv*3+j] - pos[snd*3+j] + shift) * (1.0f/CUTR);
  }
  float len = sqrtf(R[0]*R[0] + R[1]*R[1] + R[2]*R[2]);
  float mk   = (len > 0.0f) ? 1.0f : 0.0f;
  float safe = (len > 0.0f) ? len  : 1.0f;
  float inv  = 1.0f / safe;
  const float sqrt3 = 1.7320508075688772f;
  float x = safe;
  float env = (x < 1.0f) ? (1.0f - 6.0f*x*x + 8.0f*x*x*x - 3.0f*x*x*x*x) : 0.0f;
  float emk = env * mk;
  const float sqrt2 = 1.4142135623730951f;
  const float PI_F = 3.14159265358979323846f;
  union { unsigned short u[8]; uint4 q; } fb;
  #pragma unroll
  for (int n = 1; n <= NBASIS; ++n)
    fb.u[n-1] = f2bf(sqrt2 * __sinf(PI_F * (float)n * safe) * inv * emk);
  ((uint4*)efeatB)[slot] = fb.q;
  ((float4*)y1mP)[slot]  = make_float4(sqrt3*R[0]*inv, sqrt3*R[1]*inv, sqrt3*R[2]*inv, mk);
  sndP[slot] = snd;
}

// ---------------- weight prep: fp32 -> bf16 B-fragment layout for all 3 layers ----------------
// B-frag for 16x16x32: lane L holds B[k=(L>>4)*8+j][n=L&15], j=0..7.
__global__ void k_wprep(const float* __restrict__ Wr1, const float* __restrict__ Wr2,
                        const float* __restrict__ Wr3, unsigned short* __restrict__ wfrag)
{
  int gid = blockIdx.x * 256 + threadIdx.x;
  if (gid >= 3 * WPL) return;
  int l = gid / WPL, r = gid % WPL;
  float val;
  if (r < 2048) {               // Wr1f: 4 frags (ct), K padded 8->32 with zeros
    int f = r >> 9, wi = r & 511, L = wi >> 3, j = wi & 7;
    int k = (L >> 4) * 8 + j, n = L & 15, ct = f;
    val = (k < 8) ? Wr1[l*512 + k*64 + ct*16 + n] : 0.0f;
  } else if (r < 6144) {        // Wr2f: 8 frags (kt*4+ct)
    int r2 = r - 2048;
    int f = r2 >> 9, wi = r2 & 511, L = wi >> 3, j = wi & 7;
    int kt = f >> 2, ct = f & 3;
    int k = kt*32 + (L >> 4)*8 + j, n = L & 15;
    val = Wr2[l*4096 + k*64 + ct*16 + n];
  } else {                      // Wr3f: 32 frags (kt*16+ct), row length 256
    int r3 = r - 6144;
    int f = r3 >> 9, wi = r3 & 511, L = wi >> 3, j = wi & 7;
    int kt = f >> 4, ct = f & 15;
    int k = kt*32 + (L >> 4)*8 + j, n = L & 15;
    val = Wr3[l*16384 + k*256 + ct*16 + n];
  }
  wfrag[gid] = f2bf(val);
}

// ---------------- tables: xf per species, layer-0 s_up per species ----------------
__global__ void k_tables(const float* __restrict__ W_embed, const float* __restrict__ W_x,
                         const float* __restrict__ Wus0,
                         float* __restrict__ T, float* __restrict__ Tup0)
{
  int t = threadIdx.x; int sp = t >> 6, o = t & 63;
  float a = 0.0f, b = 0.0f;
  for (int cc = 0; cc < 64; ++cc) {
    float e = W_embed[sp*64 + cc];
    a += e * W_x[cc*64 + o];
    b += e * Wus0[cc*64 + o];
  }
  T[t] = a; Tup0[t] = b;
}

__global__ void k_embed0(const int* __restrict__ species, const float* __restrict__ W_embed,
                         const float* __restrict__ Tup0,
                         float* __restrict__ s, float4* __restrict__ nodeP)
{
  int gid = blockIdx.x * 256 + threadIdx.x;
  if (gid >= NN * 64) return;
  int n = gid >> 6, c = gid & 63;
  int sp = species[n];
  s[gid] = W_embed[sp*64 + c];
  nodeP[gid] = make_float4(Tup0[sp*64 + c], 0.0f, 0.0f, 0.0f);   // v=0 at layer 0
}

// ---------------- gather: MFMA radial MLP + messages + aggregation ----------------
// 8 waves/WG (512 thr), wave per node, 16-edge node-aligned tiles (sorted -> deterministic).
// XCD swizzle: block b -> graph b%8 (dispatch round-robin => XCD b%8); one graph's nodeP
// (2.5 MB) lives in that XCD's 4 MB L2 -> sender-gather is L2-resident (r8: FETCH 31 MB).
// launch_bounds(512,3): 170-reg cap -> 3 waves/SIMD (r8 was (512,2)=2 waves, latency-bound).
// np loads software-pipelined one ctm ahead (16+16 regs live, vs 64 for whole-tile prefetch).
// A-layout: A[m=lane&15][k=quad*8+j]; C/D: col=lane&15, row=quad*4+reg (m89/m120 verified).
__global__ __launch_bounds__(512, 3) void k_gather(
    const int* __restrict__ rowptrP,
    const unsigned short* __restrict__ efeatB, const float4* __restrict__ y1mP,
    const int* __restrict__ sndP, const float4* __restrict__ nodeP,
    const unsigned short* __restrict__ wfrag,
    const float* __restrict__ br1, const float* __restrict__ br2,
    float4* __restrict__ aggP)
{
  __shared__ unsigned short smw[WPL];          // 45056 B: Wr1f | Wr2f | Wr3f
  __shared__ float smf[128];                   // br1 | br2
  __shared__ unsigned short rtAll[8*16*RTS];   // 22528 B: per-wave MFMA roundtrip
  __shared__ float4 ymAll[8*16];               // 2048 B: per-wave y1m tile
  __shared__ int sndAll[8*16];                 // 512 B: per-wave snd tile
  int tid = threadIdx.x;
  if (tid < 64) { smf[tid] = br1[tid]; smf[64+tid] = br2[tid]; }
  {
    const unsigned* src = (const unsigned*)wfrag;
    unsigned* dst = (unsigned*)smw;
    for (int i = tid; i < WPL/2; i += 512) dst[i] = src[i];
  }
  __syncthreads();
  const unsigned short* Wr1f = smw;
  const unsigned short* Wr2f = smw + 2048;
  const unsigned short* Wr3f = smw + 6144;

  int w = tid >> 6, lane = tid & 63;
  int n16 = lane & 15, quad = lane >> 4;
  unsigned short* rt = rtAll + w*16*RTS;
  float4* ym = ymAll + w*16;
  int* sndL = sndAll + w*16;
  // XCD swizzle: graph = blockIdx%8, node-within-graph = (blockIdx/8)*8 + wave
  int g = blockIdx.x & 7, rr = (blockIdx.x >> 3)*8 + w;
  if (rr < NPG) {
  int r = g*NPG + rr;
  int start = rowptrP[r], end = rowptrP[r+1];
  float as[4] = {0,0,0,0};
  float av[4][3] = {{0,0,0},{0,0,0},{0,0,0},{0,0,0}};
  const float inv_sqrt3 = 0.5773502691896258f;

  for (int e0 = start; e0 < end; e0 += 16) {
    // stage edge meta in per-wave LDS (in-wave lockstep; DS ops are in-order per wave)
    if (quad == 1) ym[n16] = y1mP[e0 + n16];
    if (quad == 2) sndL[n16] = sndP[e0 + n16];
    // efeat A-frag: quad0 = k 0..7 (real), quads 1-3 = k 8..31 (zero; Wr1f zero-padded too)
    bf16x8 aef = (bf16x8){0,0,0,0,0,0,0,0};
    if (quad == 0)
      aef = *(const bf16x8*)(efeatB + (size_t)(e0 + n16)*8);
    // ---- h1 = silu(efeat @ Wr1 + b1): 4 MFMAs ----
    f32x4 hacc[4];
    #pragma unroll
    for (int ct = 0; ct < 4; ++ct) {
      bf16x8 bf = *(const bf16x8*)(Wr1f + (ct*64 + lane)*8);
      hacc[ct] = __builtin_amdgcn_mfma_f32_16x16x32_bf16(aef, bf, (f32x4){0,0,0,0}, 0, 0, 0);
    }
    #pragma unroll
    for (int ct = 0; ct < 4; ++ct) {
      int ch = ct*16 + n16;
      float b = smf[ch];
      #pragma unroll
      for (int reg = 0; reg < 4; ++reg)
        rt[(quad*4 + reg)*RTS + ch] = f2bf(silu_f(hacc[ct][reg] + b));
    }
    bf16x8 a1[2];    // wave-lockstep LDS roundtrip (per-wave buffer, no barrier)
    #pragma unroll
    for (int kt = 0; kt < 2; ++kt)
      a1[kt] = *(const bf16x8*)(rt + n16*RTS + kt*32 + quad*8);
    // ---- h2 = silu(h1 @ Wr2 + b2): 8 MFMAs ----
    #pragma unroll
    for (int ct = 0; ct < 4; ++ct) {
      bf16x8 b0 = *(const bf16x8*)(Wr2f + ((0*4 + ct)*64 + lane)*8);
      bf16x8 b1 = *(const bf16x8*)(Wr2f + ((1*4 + ct)*64 + lane)*8);
      f32x4 acc = __builtin_amdgcn_mfma_f32_16x16x32_bf16(a1[0], b0, (f32x4){0,0,0,0}, 0, 0, 0);
      hacc[ct]  = __builtin_amdgcn_mfma_f32_16x16x32_bf16(a1[1], b1, acc, 0, 0, 0);
    }
    #pragma unroll
    for (int ct = 0; ct < 4; ++ct) {
      int ch = ct*16 + n16;
      float b = smf[64 + ch];
      #pragma unroll
      for (int reg = 0; reg < 4; ++reg)
        rt[(quad*4 + reg)*RTS + ch] = f2bf(silu_f(hacc[ct][reg] + b));
    }
    bf16x8 a2[2];
    #pragma unroll
    for (int kt = 0; kt < 2; ++kt)
      a2[kt] = *(const bf16x8*)(rt + n16*RTS + kt*32 + quad*8);
    // ---- wts = h2 @ Wr3 per channel-group; np software-pipelined one ctm ahead ----
    float4 np[4];
    #pragma unroll
    for (int j = 0; j < 4; ++j)
      np[j] = nodeP[(size_t)sndL[quad*4 + j]*64 + n16];
    #pragma unroll
    for (int ctm = 0; ctm < 4; ++ctm) {
      float4 npc[4];
      #pragma unroll
      for (int j = 0; j < 4; ++j) npc[j] = np[j];
      if (ctm < 3) {
        #pragma unroll
        for (int j = 0; j < 4; ++j)
          np[j] = nodeP[(size_t)sndL[quad*4 + j]*64 + (ctm+1)*16 + n16];
      }
      f32x4 wacc[4];
      #pragma unroll
      for (int p = 0; p < 4; ++p) {
        int ct = p*4 + ctm;      // path p, channels ctm*16..+15
        f32x4 acc = __builtin_amdgcn_mfma_f32_16x16x32_bf16(
            a2[0], *(const bf16x8*)(Wr3f + ((0*16 + ct)*64 + lane)*8), (f32x4){0,0,0,0}, 0, 0, 0);
        wacc[p] = __builtin_amdgcn_mfma_f32_16x16x32_bf16(
            a2[1], *(const bf16x8*)(Wr3f + ((1*16 + ct)*64 + lane)*8), acc, 0, 0, 0);
      }
      #pragma unroll
      for (int j = 0; j < 4; ++j) {   // C row = quad*4+j = edge e0+quad*4+j
        float4 y = ym[quad*4 + j];    // broadcast LDS read
        float4 npv = npc[j];
        float mk = y.w;
        float w0 = wacc[0][j]*mk, w1 = wacc[1][j]*mk, w2 = wacc[2][j]*mk, w3 = wacc[3][j]*mk;
        float dot = npv.y*y.x + npv.z*y.y + npv.w*y.z;
        float t2 = w2*npv.x;
        as[ctm]    += w0*npv.x + w1*dot*inv_sqrt3;
        av[ctm][0] += t2*y.x + w3*npv.y;
        av[ctm][1] += t2*y.y + w3*npv.z;
        av[ctm][2] += t2*y.z + w3*npv.w;
      }
      __builtin_amdgcn_sched_barrier(0);   // keep ctm iterations from interleaving (reg cap)
    }
  }
  // cross-quad butterfly + write packed agg
  const float invavg = 1.0f / AVGN;
  #pragma unroll
  for (int ctm = 0; ctm < 4; ++ctm) {
    float v0 = as[ctm], v1 = av[ctm][0], v2 = av[ctm][1], v3 = av[ctm][2];
    v0 += __shfl_xor(v0, 16); v0 += __shfl_xor(v0, 32);
    v1 += __shfl_xor(v1, 16); v1 += __shfl_xor(v1, 32);
    v2 += __shfl_xor(v2, 16); v2 += __shfl_xor(v2, 32);
    v3 += __shfl_xor(v3, 16); v3 += __shfl_xor(v3, 32);
    if (quad == 0)
      aggP[(size_t)r*64 + ctm*16 + n16] =
          make_float4(v0*invavg, v1*invavg, v2*invavg, v3*invavg);
  }
  }  // rr < NPG
}

// ---------------- post: msg/sc/product + readout + NEXT layer's up-projection ----------------
// 6 shared weight matrices staged in 96 KB LDS once per block (r8: 20000 waves x 160 KB
// re-streamed from L2 ~= 3.2 GB/layer was the k_post bottleneck). Species sc stays global (L2).
__global__ __launch_bounds__(512, 1) void k_post(
    const float4* __restrict__ aggP, const int* __restrict__ species,
    const float* __restrict__ T,
    float* __restrict__ s, float* __restrict__ v,
    const float* __restrict__ Wms, const float* __restrict__ Wmv,
    const float* __restrict__ Wscs, const float* __restrict__ Wscv,
    const float* __restrict__ Wps, const float* __restrict__ Wpv,
    const float* __restrict__ Wread,
    const float* __restrict__ Wus_n, const float* __restrict__ Wuv_n,
    float4* __restrict__ nodeP, float* __restrict__ acc_out, int has_next)
{
  __shared__ float wlds[6*4096];   // 96 KB: Wms|Wmv|Wps|Wpv|Wus|Wuv
  __shared__ float lds[8*1024];    // 32 KB feature buffers
  int tid = threadIdx.x; int w = tid >> 6, c = tid & 63;
  {
    const float4* s0 = (const float4*)Wms;  const float4* s1 = (const float4*)Wmv;
    const float4* s2 = (const float4*)Wps;  const float4* s3 = (const float4*)Wpv;
    const float4* s4 = (const float4*)Wus_n; const float4* s5 = (const float4*)Wuv_n;
    float4* d = (float4*)wlds;
    for (int i = tid; i < 1024; i += 512) {
      d[i] = s0[i]; d[1024+i] = s1[i]; d[2048+i] = s2[i];
      d[3072+i] = s3[i]; d[4096+i] = s4[i]; d[5120+i] = s5[i];
    }
  }
  __syncthreads();
  const float* wms = wlds;
  const float* wmv = wlds + 4096;
  const float* wps = wlds + 8192;
  const float* wpv = wlds + 12288;
  const float* wus = wlds + 16384;
  const float* wuv = wlds + 20480;
  float* asb = lds + w*1024;   // 64
  float* avb = asb + 64;       // 192
  float* sob = avb + 192;      // 64
  float* vob = sob + 64;       // 192
  float* tsb = vob + 192;      // 64
  float* tvb = tsb + 64;       // 192
  float* snb = tvb + 192;      // 64
  float* vnb = snb + 64;       // 192
  int n = blockIdx.x*8 + w;
  int sp = species[n];
  float4 ag = aggP[(size_t)n*64 + c];
  asb[c] = ag.x; avb[c] = ag.y; avb[64+c] = ag.z; avb[128+c] = ag.w;
  sob[c] = s[n*64 + c];
  #pragma unroll
  for (int m = 0; m < 3; ++m) vob[m*64 + c] = v[(n*3 + m)*64 + c];
  // wave-lockstep LDS (per-wave region, no barrier)
  float ms = 0, mv0 = 0, mv1 = 0, mv2 = 0;
  for (int k = 0; k < 64; ++k) {
    float wm = wms[k*64 + c];
    ms  += asb[k]*wm;
    float wv = wmv[k*64 + c];
    mv0 += avb[k]*wv; mv1 += avb[64+k]*wv; mv2 += avb[128+k]*wv;
  }
  float xf = T[sp*64 + c];
  tsb[c] = xf*ms; tvb[c] = xf*mv0; tvb[64+c] = xf*mv1; tvb[128+c] = xf*mv2;
  const float* Wss = Wscs + sp*4096;
  const float* Wsv = Wscv + sp*4096;
  float sn_ = 0, vn0 = 0, vn1 = 0, vn2 = 0;
  for (int k = 0; k < 64; ++k) {
    float wp  = wps[k*64 + c];  sn_ += tsb[k]*wp;
    float wsc = Wss[k*64 + c];  sn_ += sob[k]*wsc;
    float wpv_ = wpv[k*64 + c];
    vn0 += tvb[k]*wpv_; vn1 += tvb[64+k]*wpv_; vn2 += tvb[128+k]*wpv_;
    float wsv = Wsv[k*64 + c];
    vn0 += vob[k]*wsv; vn1 += vob[64+k]*wsv; vn2 += vob[128+k]*wsv;
  }
  s[n*64 + c] = sn_;
  v[(n*3+0)*64 + c] = vn0; v[(n*3+1)*64 + c] = vn1; v[(n*3+2)*64 + c] = vn2;
  snb[c] = sn_; vnb[c] = vn0; vnb[64+c] = vn1; vnb[128+c] = vn2;
  if (c < 9) {                         // readout, silu-accumulated across layers
    int o3 = c / 3, m = c % 3;
    const float* wr = Wread + o3*64;
    float a = 0.0f;
    for (int k = 0; k < 64; ++k) a += vnb[m*64 + k]*wr[k];
    acc_out[n*9 + c] += silu_f(a);
  }
  if (has_next) {                      // fused up-projection for next layer
    float su = 0, u0 = 0, u1 = 0, u2 = 0;
    for (int k = 0; k < 64; ++k) {
      float wu = wus[k*64 + c]; su += snb[k]*wu;
      float wv = wuv[k*64 + c];
      u0 += vnb[k]*wv; u1 += vnb[64+k]*wv; u2 += vnb[128+k]*wv;
    }
    nodeP[(size_t)n*64 + c] = make_float4(su, u0, u1, u2);
  }
}

// ---------------- final graph reduction ----------------
__global__ void k_final(const float* __restrict__ acc_out, float* __restrict__ out)
{
  __shared__ float red[256];
  int g = blockIdx.x / 9, j = blockIdx.x % 9;
  int tid = threadIdx.x;
  float a = 0.0f;
  for (int n = g*NPG + tid; n < (g + 1)*NPG; n += 256) a += acc_out[n*9 + j];
  red[tid] = a; __syncthreads();
  for (int off = 128; off > 0; off >>= 1) {
    if (tid < off) red[tid] += red[tid + off];
    __syncthreads();
  }
  if (tid == 0) out[g*9 + j] = red[0];
}

extern "C" void kernel_launch(void* const* d_in, const int* in_sizes, int n_in,
                              void* d_out, int out_size, void* d_ws, size_t ws_size,
                              hipStream_t stream)
{
  const float* pos     = (const float*)d_in[0];
  const float* cell    = (const float*)d_in[1];
  const float* Sij     = (const float*)d_in[2];
  const float* W_embed = (const float*)d_in[3];
  const float* W_x     = (const float*)d_in[4];
  const float* W_up_s  = (const float*)d_in[5];
  const float* W_up_v  = (const float*)d_in[6];
  const float* Wr1     = (const float*)d_in[7];
  const float* br1     = (const float*)d_in[8];
  const float* Wr2     = (const float*)d_in[9];
  const float* br2     = (const float*)d_in[10];
  const float* Wr3     = (const float*)d_in[11];
  const float* W_msg_s = (const float*)d_in[12];
  const float* W_msg_v = (const float*)d_in[13];
  const float* W_sc_s  = (const float*)d_in[14];
  const float* W_sc_v  = (const float*)d_in[15];
  const float* W_p_s   = (const float*)d_in[16];
  const float* W_p_v   = (const float*)d_in[17];
  const float* W_read  = (const float*)d_in[18];
  const int*   ei      = (const int*)d_in[19];
  const int*   batch   = (const int*)d_in[20];
  const int*   species = (const int*)d_in[21];
  float* out = (float*)d_out;

  char* ws = (char*)d_ws;
  size_t off = 0;
  auto alloc = [&](size_t bytes) -> void* {
    void* p = ws + off;
    off += (bytes + 255) & ~(size_t)255;
    return p;
  };
  unsigned short* efeatB = (unsigned short*)alloc((size_t)EPAD*8*2);
  float* y1mP    = (float*)alloc((size_t)EPAD*4*4);
  int*   sndP    = (int*)alloc((size_t)EPAD*4);
  unsigned* csrE = (unsigned*)alloc((size_t)EPAD*4);
  float* sF      = (float*)alloc((size_t)NN*64*4);
  float* vF      = (float*)alloc((size_t)NN*192*4);
  float4* nodeP  = (float4*)alloc((size_t)NN*64*16);
  float4* aggP   = (float4*)alloc((size_t)NN*64*16);
  float* acc_out = (float*)alloc((size_t)NN*9*4);
  float* T       = (float*)alloc(512*4);
  float* Tup0    = (float*)alloc(512*4);
  unsigned short* wfrag = (unsigned short*)alloc((size_t)3*WPL*2);
  int* deg     = (int*)alloc((size_t)NN*4);
  int* rowptrP = (int*)alloc((size_t)(NN+1)*4);
  int* cursor  = (int*)alloc((size_t)NN*4);

  hipMemsetAsync(deg, 0, (size_t)NN*4, stream);
  hipMemsetAsync(vF, 0, (size_t)NN*192*4, stream);
  hipMemsetAsync(acc_out, 0, (size_t)NN*9*4, stream);
  hipMemsetAsync(csrE, 0xFF, (size_t)EPAD*4, stream);   // pads sort to row tail

  k_count<<<EE/256, 256, 0, stream>>>(ei, deg);
  k_scan <<<1, 1024, 0, stream>>>(deg, rowptrP, cursor);
  k_scatter <<<EE/256, 256, 0, stream>>>(ei, cursor, csrE);
  k_sortrows<<<NN/8, 512, 0, stream>>>(rowptrP, csrE);
  k_geom_slot<<<(EPAD+255)/256, 256, 0, stream>>>(pos, cell, Sij, ei, batch, csrE,
                                                  efeatB, y1mP, sndP);
  k_wprep <<<(3*WPL)/256, 256, 0, stream>>>(Wr1, Wr2, Wr3, wfrag);
  k_tables<<<1, 512, 0, stream>>>(W_embed, W_x, W_up_s, T, Tup0);
  k_embed0<<<NN*64/256, 256, 0, stream>>>(species, W_embed, Tup0, sF, nodeP);

  const int GATHER_BLOCKS = 8 * ((NPG + 7) / 8);   // 2504: graph = b%8 (XCD swizzle)
  for (int l = 0; l < NLAYERS; ++l) {
    k_gather<<<GATHER_BLOCKS, 512, 0, stream>>>(rowptrP, efeatB, (const float4*)y1mP, sndP,
                                                nodeP, wfrag + l*WPL, br1 + l*64, br2 + l*64, aggP);
    int has_next = (l < NLAYERS-1) ? 1 : 0;
    const float* Wus_n = W_up_s + (has_next ? (l+1)*4096 : l*4096);
    const float* Wuv_n = W_up_v + (has_next ? (l+1)*4096 : l*4096);
    k_post<<<2500, 512, 0, stream>>>(aggP, species, T, sF, vF,
                                     W_msg_s + l*4096, W_msg_v + l*4096,
                                     W_sc_s + l*32768, W_sc_v + l*32768,
                                     W_p_s + l*4096, W_p_v + l*4096,
                                     W_read + l*192, Wus_n, Wuv_n,
                                     nodeP, acc_out, has_next);
  }
  k_final<<<72, 256, 0, stream>>>(acc_out, out);
}

// Round 10
// 1305.449 us; speedup vs baseline: 1.0294x; 1.0294x over previous
//
#include <hip/hip_runtime.h>
#include <math.h>

#define NN 20000
#define GG 8
#define NPG 2500
#define EE 640000
#define EPAD 944000   // upper bound: E + 15*NN, per-node degree padded to mult of 16
#define NLAYERS 3
#define CUTR 6.0f
#define AVGN 32.0f
#define NBASIS 8
#define WPL 22528     // ushorts of frag-layout weights per layer (Wr1f 2048 + Wr2f 4096 + Wr3f 16384)
#define RTS 88        // shorts per roundtrip row (16B-aligned, breaks 8-way bank conflict of 80)

typedef short bf16x8 __attribute__((ext_vector_type(8)));
typedef float f32x4 __attribute__((ext_vector_type(4)));

__device__ __forceinline__ float silu_f(float x){ return x / (1.0f + __expf(-x)); }
__device__ __forceinline__ unsigned short f2bf(float f){
  union { float f; unsigned u; } x; x.f = f;
  unsigned r = x.u + 0x7FFFu + ((x.u >> 16) & 1u);   // RNE
  return (unsigned short)(r >> 16);
}

// ---------------- CSR degree count ----------------
__global__ void k_count(const int* __restrict__ ei, int* __restrict__ deg)
{
  int e = blockIdx.x * 256 + threadIdx.x;
  if (e >= EE) return;
  atomicAdd(&deg[ei[EE + e]], 1);
}

// padded scan: each row's extent rounded up to multiple of 16 (tiles never cross nodes)
__global__ void k_scan(const int* __restrict__ deg, int* __restrict__ rowptrP,
                       int* __restrict__ cursor)
{
  __shared__ int buf[1024];
  __shared__ int carry;
  int tid = threadIdx.x;
  if (tid == 0) carry = 0;
  __syncthreads();
  for (int base = 0; base < NN; base += 1024) {
    int i = base + tid;
    int x = (i < NN) ? ((deg[i] + 15) & ~15) : 0;
    buf[tid] = x; __syncthreads();
    for (int off = 1; off < 1024; off <<= 1) {
      int t = (tid >= off) ? buf[tid - off] : 0;
      __syncthreads();
      buf[tid] += t;
      __syncthreads();
    }
    int incl = buf[tid];
    int c = carry;
    __syncthreads();
    if (i < NN) { rowptrP[i] = c + incl - x; cursor[i] = c + incl - x; }
    if (tid == 1023) carry = c + incl;
    __syncthreads();
  }
  if (tid == 0) rowptrP[NN] = carry;
}

// ---------------- scatter edge ids into padded CSR slots (perm nondeterministic) ----------------
__global__ void k_scatter(const int* __restrict__ ei, int* __restrict__ cursor,
                          unsigned* __restrict__ csrE)
{
  int e = blockIdx.x * 256 + threadIdx.x;
  if (e >= EE) return;
  int slot = atomicAdd(&cursor[ei[EE + e]], 1);
  csrE[slot] = (unsigned)e;
}

// ---------------- per-row sort by edge id -> DETERMINISTIC slot assignment ----------------
__global__ __launch_bounds__(512) void k_sortrows(const int* __restrict__ rowptrP,
                                                  unsigned* __restrict__ csrE)
{
  __shared__ unsigned buf[8*512];
  int w = threadIdx.x >> 6, lane = threadIdx.x & 63;
  unsigned* b = buf + w*512;
  int r = blockIdx.x*8 + w;
  int start = rowptrP[r], end = rowptrP[r+1];
  int P = end - start;
  if (P < 2 || P > 512) return;   // max padded degree << 512 for this input
  for (int i = lane; i < P; i += 64) b[i] = csrE[start + i];
  for (int pass = 0; pass < P; ++pass) {
    int par = pass & 1;
    for (int i = lane; 2*i + par + 1 < P; i += 64) {
      int idx = 2*i + par;
      unsigned a = b[idx], c = b[idx+1];
      if (a > c) { b[idx] = c; b[idx+1] = a; }
    }
  }
  for (int i = lane; i < P; i += 64) csrE[start + i] = b[i];
}

// ---------------- geometry per SLOT (deterministic values; pads -> zeros) ----------------
__global__ void k_geom_slot(const float* __restrict__ pos, const float* __restrict__ cell,
                            const float* __restrict__ Sij, const int* __restrict__ ei,
                            const int* __restrict__ batch, const unsigned* __restrict__ csrE,
                            unsigned short* __restrict__ efeatB, float* __restrict__ y1mP,
                            int* __restrict__ sndP)
{
  int slot = blockIdx.x * 256 + threadIdx.x;
  if (slot >= EPAD) return;
  int e = (int)csrE[slot];
  if (e < 0) {
    ((uint4*)efeatB)[slot] = make_uint4(0,0,0,0);
    ((float4*)y1mP)[slot]  = make_float4(0,0,0,0);
    sndP[slot] = 0;
    return;
  }
  int snd = ei[e], rcv = ei[EE + e];
  int g = batch[snd];
  float s0 = Sij[e*3+0], s1 = Sij[e*3+1], s2_ = Sij[e*3+2];
  const float* cg = cell + g*9;
  float R[3];
  #pragma unroll
  for (int j = 0; j < 3; ++j) {
    float shift = s0*cg[0*3+j] + s1*cg[1*3+j] + s2_*cg[2*3+j];
    R[j] = (pos[rcv*3+j] - pos[snd*3+j] + shift) * (1.0f/CUTR);
  }
  float len = sqrtf(R[0]*R[0] + R[1]*R[1] + R[2]*R[2]);
  float mk   = (len > 0.0f) ? 1.0f : 0.0f;
  float safe = (len > 0.0f) ? len  : 1.0f;
  float inv  = 1.0f / safe;
  const float sqrt3 = 1.7320508075688772f;
  float x = safe;
  float env = (x < 1.0f) ? (1.0f - 6.0f*x*x + 8.0f*x*x*x - 3.0f*x*x*x*x) : 0.0f;
  float emk = env * mk;
  const float sqrt2 = 1.4142135623730951f;
  const float PI_F = 3.14159265358979323846f;
  union { unsigned short u[8]; uint4 q; } fb;
  #pragma unroll
  for (int n = 1; n <= NBASIS; ++n)
    fb.u[n-1] = f2bf(sqrt2 * __sinf(PI_F * (float)n * safe) * inv * emk);
  ((uint4*)efeatB)[slot] = fb.q;
  ((float4*)y1mP)[slot]  = make_float4(sqrt3*R[0]*inv, sqrt3*R[1]*inv, sqrt3*R[2]*inv, mk);
  sndP[slot] = snd;
}

// ---------------- weight prep: fp32 -> bf16 B-fragment layout for all 3 layers ----------------
// B-frag for 16x16x32: lane L holds B[k=(L>>4)*8+j][n=L&15], j=0..7.
__global__ void k_wprep(const float* __restrict__ Wr1, const float* __restrict__ Wr2,
                        const float* __restrict__ Wr3, unsigned short* __restrict__ wfrag)
{
  int gid = blockIdx.x * 256 + threadIdx.x;
  if (gid >= 3 * WPL) return;
  int l = gid / WPL, r = gid % WPL;
  float val;
  if (r < 2048) {               // Wr1f: 4 frags (ct), K padded 8->32 with zeros
    int f = r >> 9, wi = r & 511, L = wi >> 3, j = wi & 7;
    int k = (L >> 4) * 8 + j, n = L & 15, ct = f;
    val = (k < 8) ? Wr1[l*512 + k*64 + ct*16 + n] : 0.0f;
  } else if (r < 6144) {        // Wr2f: 8 frags (kt*4+ct)
    int r2 = r - 2048;
    int f = r2 >> 9, wi = r2 & 511, L = wi >> 3, j = wi & 7;
    int kt = f >> 2, ct = f & 3;
    int k = kt*32 + (L >> 4)*8 + j, n = L & 15;
    val = Wr2[l*4096 + k*64 + ct*16 + n];
  } else {                      // Wr3f: 32 frags (kt*16+ct), row length 256
    int r3 = r - 6144;
    int f = r3 >> 9, wi = r3 & 511, L = wi >> 3, j = wi & 7;
    int kt = f >> 4, ct = f & 15;
    int k = kt*32 + (L >> 4)*8 + j, n = L & 15;
    val = Wr3[l*16384 + k*256 + ct*16 + n];
  }
  wfrag[gid] = f2bf(val);
}

// ---------------- species perm: counting sort (order within bin irrelevant) ----------------
__global__ void k_spcount(const int* __restrict__ species, int* __restrict__ hist)
{
  int n = blockIdx.x * 256 + threadIdx.x;
  if (n >= NN) return;
  atomicAdd(&hist[species[n]], 1);
}

__global__ void k_spscan(const int* __restrict__ hist, int* __restrict__ spcur)
{
  if (threadIdx.x == 0) {
    int off = 0;
    for (int i = 0; i < 8; ++i) { spcur[i] = off; off += hist[i]; }
  }
}

__global__ void k_spscatter(const int* __restrict__ species, int* __restrict__ spcur,
                            int* __restrict__ perm)
{
  int n = blockIdx.x * 256 + threadIdx.x;
  if (n >= NN) return;
  int slot = atomicAdd(&spcur[species[n]], 1);
  perm[slot] = n;   // order within species bin is nondeterministic but output-invariant
}

// ---------------- tables: xf per species, layer-0 s_up per species ----------------
__global__ void k_tables(const float* __restrict__ W_embed, const float* __restrict__ W_x,
                         const float* __restrict__ Wus0,
                         float* __restrict__ T, float* __restrict__ Tup0)
{
  int t = threadIdx.x; int sp = t >> 6, o = t & 63;
  float a = 0.0f, b = 0.0f;
  for (int cc = 0; cc < 64; ++cc) {
    float e = W_embed[sp*64 + cc];
    a += e * W_x[cc*64 + o];
    b += e * Wus0[cc*64 + o];
  }
  T[t] = a; Tup0[t] = b;
}

__global__ void k_embed0(const int* __restrict__ species, const float* __restrict__ W_embed,
                         const float* __restrict__ Tup0,
                         float* __restrict__ s, float4* __restrict__ nodeP)
{
  int gid = blockIdx.x * 256 + threadIdx.x;
  if (gid >= NN * 64) return;
  int n = gid >> 6, c = gid & 63;
  int sp = species[n];
  s[gid] = W_embed[sp*64 + c];
  nodeP[gid] = make_float4(Tup0[sp*64 + c], 0.0f, 0.0f, 0.0f);   // v=0 at layer 0
}

// ---------------- gather: MFMA radial MLP + messages + aggregation (round-8 exact) ----------------
// (512,2) = 256-reg wave, whole-tile np prefetch, sched_barrier per ctm: zero spill (r8:
// WRITE 69 MB). (512,3) re-spilled (r9: WRITE 211 MB) — do not raise occupancy here.
// XCD swizzle: block b -> graph b%8; one graph's nodeP (2.5 MB) lives in that XCD's L2.
// A-layout: A[m=lane&15][k=quad*8+j]; C/D: col=lane&15, row=quad*4+reg (m89/m120 verified).
__global__ __launch_bounds__(512, 2) void k_gather(
    const int* __restrict__ rowptrP,
    const unsigned short* __restrict__ efeatB, const float4* __restrict__ y1mP,
    const int* __restrict__ sndP, const float4* __restrict__ nodeP,
    const unsigned short* __restrict__ wfrag,
    const float* __restrict__ br1, const float* __restrict__ br2,
    float4* __restrict__ aggP)
{
  __shared__ unsigned short smw[WPL];          // 45056 B: Wr1f | Wr2f | Wr3f
  __shared__ float smf[128];                   // br1 | br2
  __shared__ unsigned short rtAll[8*16*RTS];   // 22528 B: per-wave MFMA roundtrip
  __shared__ float4 ymAll[8*16];               // 2048 B: per-wave y1m tile
  __shared__ int sndAll[8*16];                 // 512 B: per-wave snd tile
  int tid = threadIdx.x;
  if (tid < 64) { smf[tid] = br1[tid]; smf[64+tid] = br2[tid]; }
  {
    const unsigned* src = (const unsigned*)wfrag;
    unsigned* dst = (unsigned*)smw;
    for (int i = tid; i < WPL/2; i += 512) dst[i] = src[i];
  }
  __syncthreads();
  const unsigned short* Wr1f = smw;
  const unsigned short* Wr2f = smw + 2048;
  const unsigned short* Wr3f = smw + 6144;

  int w = tid >> 6, lane = tid & 63;
  int n16 = lane & 15, quad = lane >> 4;
  unsigned short* rt = rtAll + w*16*RTS;
  float4* ym = ymAll + w*16;
  int* sndL = sndAll + w*16;
  // XCD swizzle: graph = blockIdx%8, node-within-graph = (blockIdx/8)*8 + wave
  int g = blockIdx.x & 7, rr = (blockIdx.x >> 3)*8 + w;
  if (rr < NPG) {
  int r = g*NPG + rr;
  int start = rowptrP[r], end = rowptrP[r+1];
  float as[4] = {0,0,0,0};
  float av[4][3] = {{0,0,0},{0,0,0},{0,0,0},{0,0,0}};
  const float inv_sqrt3 = 0.5773502691896258f;

  for (int e0 = start; e0 < end; e0 += 16) {
    // stage edge meta in per-wave LDS (in-wave lockstep; DS ops are in-order per wave)
    if (quad == 1) ym[n16] = y1mP[e0 + n16];
    if (quad == 2) sndL[n16] = sndP[e0 + n16];
    // prefetch sender rows for the whole tile (issued early; h1/h2 MFMAs hide latency)
    float4 np[4][4];
    #pragma unroll
    for (int ctm = 0; ctm < 4; ++ctm)
      #pragma unroll
      for (int j = 0; j < 4; ++j)
        np[ctm][j] = nodeP[(size_t)sndL[quad*4 + j]*64 + ctm*16 + n16];
    // efeat A-frag: quad0 = k 0..7 (real), quads 1-3 = k 8..31 (zero; Wr1f zero-padded too)
    bf16x8 aef = (bf16x8){0,0,0,0,0,0,0,0};
    if (quad == 0)
      aef = *(const bf16x8*)(efeatB + (size_t)(e0 + n16)*8);
    // ---- h1 = silu(efeat @ Wr1 + b1): 4 MFMAs ----
    f32x4 hacc[4];
    #pragma unroll
    for (int ct = 0; ct < 4; ++ct) {
      bf16x8 bf = *(const bf16x8*)(Wr1f + (ct*64 + lane)*8);
      hacc[ct] = __builtin_amdgcn_mfma_f32_16x16x32_bf16(aef, bf, (f32x4){0,0,0,0}, 0, 0, 0);
    }
    #pragma unroll
    for (int ct = 0; ct < 4; ++ct) {
      int ch = ct*16 + n16;
      float b = smf[ch];
      #pragma unroll
      for (int reg = 0; reg < 4; ++reg)
        rt[(quad*4 + reg)*RTS + ch] = f2bf(silu_f(hacc[ct][reg] + b));
    }
    bf16x8 a1[2];    // wave-lockstep LDS roundtrip (per-wave buffer, no barrier)
    #pragma unroll
    for (int kt = 0; kt < 2; ++kt)
      a1[kt] = *(const bf16x8*)(rt + n16*RTS + kt*32 + quad*8);
    // ---- h2 = silu(h1 @ Wr2 + b2): 8 MFMAs ----
    #pragma unroll
    for (int ct = 0; ct < 4; ++ct) {
      bf16x8 b0 = *(const bf16x8*)(Wr2f + ((0*4 + ct)*64 + lane)*8);
      bf16x8 b1 = *(const bf16x8*)(Wr2f + ((1*4 + ct)*64 + lane)*8);
      f32x4 acc = __builtin_amdgcn_mfma_f32_16x16x32_bf16(a1[0], b0, (f32x4){0,0,0,0}, 0, 0, 0);
      hacc[ct]  = __builtin_amdgcn_mfma_f32_16x16x32_bf16(a1[1], b1, acc, 0, 0, 0);
    }
    #pragma unroll
    for (int ct = 0; ct < 4; ++ct) {
      int ch = ct*16 + n16;
      float b = smf[64 + ch];
      #pragma unroll
      for (int reg = 0; reg < 4; ++reg)
        rt[(quad*4 + reg)*RTS + ch] = f2bf(silu_f(hacc[ct][reg] + b));
    }
    bf16x8 a2[2];
    #pragma unroll
    for (int kt = 0; kt < 2; ++kt)
      a2[kt] = *(const bf16x8*)(rt + n16*RTS + kt*32 + quad*8);
    // ---- wts = h2 @ Wr3 per channel-group; message paths fused ----
    #pragma unroll
    for (int ctm = 0; ctm < 4; ++ctm) {
      f32x4 wacc[4];
      #pragma unroll
      for (int p = 0; p < 4; ++p) {
        int ct = p*4 + ctm;      // path p, channels ctm*16..+15
        f32x4 acc = __builtin_amdgcn_mfma_f32_16x16x32_bf16(
            a2[0], *(const bf16x8*)(Wr3f + ((0*16 + ct)*64 + lane)*8), (f32x4){0,0,0,0}, 0, 0, 0);
        wacc[p] = __builtin_amdgcn_mfma_f32_16x16x32_bf16(
            a2[1], *(const bf16x8*)(Wr3f + ((1*16 + ct)*64 + lane)*8), acc, 0, 0, 0);
      }
      #pragma unroll
      for (int j = 0; j < 4; ++j) {   // C row = quad*4+j = edge e0+quad*4+j
        float4 y = ym[quad*4 + j];    // broadcast LDS read
        float4 npv = np[ctm][j];
        float mk = y.w;
        float w0 = wacc[0][j]*mk, w1 = wacc[1][j]*mk, w2 = wacc[2][j]*mk, w3 = wacc[3][j]*mk;
        float dot = npv.y*y.x + npv.z*y.y + npv.w*y.z;
        as[ctm]    += w0*npv.x + w1*dot*inv_sqrt3;
        av[ctm][0] += w2*npv.x*y.x + w3*npv.y;
        av[ctm][1] += w2*npv.x*y.y + w3*npv.z;
        av[ctm][2] += w2*npv.x*y.z + w3*npv.w;
      }
      __builtin_amdgcn_sched_barrier(0);   // keep ctm iterations from interleaving (reg cap)
    }
  }
  // cross-quad butterfly + write packed agg
  const float invavg = 1.0f / AVGN;
  #pragma unroll
  for (int ctm = 0; ctm < 4; ++ctm) {
    float v0 = as[ctm], v1 = av[ctm][0], v2 = av[ctm][1], v3 = av[ctm][2];
    v0 += __shfl_xor(v0, 16); v0 += __shfl_xor(v0, 32);
    v1 += __shfl_xor(v1, 16); v1 += __shfl_xor(v1, 32);
    v2 += __shfl_xor(v2, 16); v2 += __shfl_xor(v2, 32);
    v3 += __shfl_xor(v3, 16); v3 += __shfl_xor(v3, 32);
    if (quad == 0)
      aggP[(size_t)r*64 + ctm*16 + n16] =
          make_float4(v0*invavg, v1*invavg, v2*invavg, v3*invavg);
  }
  }  // rr < NPG
}

// ---------------- post: msg/sc/product + readout + NEXT layer's up-projection ----------------
// 2 nodes per wave, species-sorted perm: each shared-weight load serves 2 nodes, and the
// node-pair is almost always same-species so Wsc streams amortize too (r8 bottleneck was
// ~2.56 GB/layer of L2 weight re-reads; this halves it). LDS 64 KB -> 2 blocks/CU.
// Per-node buffer layout (1024 floats): as 0 | av 64 | so 256 | vo 320 | ts 512 | tv 576 | sn 768 | vn 832
__global__ __launch_bounds__(512) void k_post(
    const float4* __restrict__ aggP, const int* __restrict__ species,
    const int* __restrict__ perm, const float* __restrict__ T,
    float* __restrict__ s, float* __restrict__ v,
    const float* __restrict__ Wms, const float* __restrict__ Wmv,
    const float* __restrict__ Wscs, const float* __restrict__ Wscv,
    const float* __restrict__ Wps, const float* __restrict__ Wpv,
    const float* __restrict__ Wread,
    const float* __restrict__ Wus_n, const float* __restrict__ Wuv_n,
    float4* __restrict__ nodeP, float* __restrict__ acc_out, int has_next)
{
  __shared__ float lds[8*2048];   // 64 KB
  int tid = threadIdx.x; int w = tid >> 6, c = tid & 63;
  float* B0 = lds + w*2048;
  float* B1 = B0 + 1024;
  int n0 = perm[blockIdx.x*16 + w*2 + 0];
  int n1 = perm[blockIdx.x*16 + w*2 + 1];
  int sp0 = species[n0], sp1 = species[n1];
  float4 ag0 = aggP[(size_t)n0*64 + c];
  float4 ag1 = aggP[(size_t)n1*64 + c];
  B0[c] = ag0.x; B0[64+c] = ag0.y; B0[128+c] = ag0.z; B0[192+c] = ag0.w;
  B1[c] = ag1.x; B1[64+c] = ag1.y; B1[128+c] = ag1.z; B1[192+c] = ag1.w;
  B0[256+c] = s[n0*64 + c];
  B1[256+c] = s[n1*64 + c];
  #pragma unroll
  for (int m = 0; m < 3; ++m) {
    B0[320 + m*64 + c] = v[(n0*3 + m)*64 + c];
    B1[320 + m*64 + c] = v[(n1*3 + m)*64 + c];
  }
  // wave-lockstep LDS (per-wave region, no barrier)
  float ms0 = 0, va0 = 0, vb0 = 0, vc0 = 0;
  float ms1 = 0, va1 = 0, vb1 = 0, vc1 = 0;
  for (int k = 0; k < 64; ++k) {
    float wm = Wms[k*64 + c];
    ms0 += B0[k]*wm; ms1 += B1[k]*wm;
    float wv = Wmv[k*64 + c];
    va0 += B0[64+k]*wv; vb0 += B0[128+k]*wv; vc0 += B0[192+k]*wv;
    va1 += B1[64+k]*wv; vb1 += B1[128+k]*wv; vc1 += B1[192+k]*wv;
  }
  float xf0 = T[sp0*64 + c], xf1 = T[sp1*64 + c];
  B0[512+c] = xf0*ms0; B0[576+c] = xf0*va0; B0[640+c] = xf0*vb0; B0[704+c] = xf0*vc0;
  B1[512+c] = xf1*ms1; B1[576+c] = xf1*va1; B1[640+c] = xf1*vb1; B1[704+c] = xf1*vc1;
  const float* Wss0 = Wscs + sp0*4096;  const float* Wsv0 = Wscv + sp0*4096;
  const float* Wss1 = Wscs + sp1*4096;  const float* Wsv1 = Wscv + sp1*4096;
  float sn0 = 0, w00 = 0, w01 = 0, w02 = 0;
  float sn1 = 0, w10 = 0, w11 = 0, w12 = 0;
  for (int k = 0; k < 64; ++k) {
    float wp = Wps[k*64 + c];
    sn0 += B0[512+k]*wp; sn1 += B1[512+k]*wp;
    float wpv = Wpv[k*64 + c];
    w00 += B0[576+k]*wpv; w01 += B0[640+k]*wpv; w02 += B0[704+k]*wpv;
    w10 += B1[576+k]*wpv; w11 += B1[640+k]*wpv; w12 += B1[704+k]*wpv;
    float ws0 = Wss0[k*64 + c];  sn0 += B0[256+k]*ws0;
    float ws1 = Wss1[k*64 + c];  sn1 += B1[256+k]*ws1;
    float wv0 = Wsv0[k*64 + c];
    w00 += B0[320+k]*wv0; w01 += B0[384+k]*wv0; w02 += B0[448+k]*wv0;
    float wv1 = Wsv1[k*64 + c];
    w10 += B1[320+k]*wv1; w11 += B1[384+k]*wv1; w12 += B1[448+k]*wv1;
  }
  s[n0*64 + c] = sn0;  s[n1*64 + c] = sn1;
  v[(n0*3+0)*64 + c] = w00; v[(n0*3+1)*64 + c] = w01; v[(n0*3+2)*64 + c] = w02;
  v[(n1*3+0)*64 + c] = w10; v[(n1*3+1)*64 + c] = w11; v[(n1*3+2)*64 + c] = w12;
  B0[768+c] = sn0; B0[832+c] = w00; B0[896+c] = w01; B0[960+c] = w02;
  B1[768+c] = sn1; B1[832+c] = w10; B1[896+c] = w11; B1[960+c] = w12;
  if (c < 9) {                         // readout, silu-accumulated across layers
    int o3 = c / 3, m = c % 3;
    const float* wr = Wread + o3*64;
    float a0 = 0.0f, a1 = 0.0f;
    for (int k = 0; k < 64; ++k) {
      a0 += B0[832 + m*64 + k]*wr[k];
      a1 += B1[832 + m*64 + k]*wr[k];
    }
    acc_out[n0*9 + c] += silu_f(a0);
    acc_out[n1*9 + c] += silu_f(a1);
  }
  if (has_next) {                      // fused up-projection for next layer
    float su0 = 0, u00 = 0, u01 = 0, u02 = 0;
    float su1 = 0, u10 = 0, u11 = 0, u12 = 0;
    for (int k = 0; k < 64; ++k) {
      float wu = Wus_n[k*64 + c];
      su0 += B0[768+k]*wu; su1 += B1[768+k]*wu;
      float wv = Wuv_n[k*64 + c];
      u00 += B0[832+k]*wv; u01 += B0[896+k]*wv; u02 += B0[960+k]*wv;
      u10 += B1[832+k]*wv; u11 += B1[896+k]*wv; u12 += B1[960+k]*wv;
    }
    nodeP[(size_t)n0*64 + c] = make_float4(su0, u00, u01, u02);
    nodeP[(size_t)n1*64 + c] = make_float4(su1, u10, u11, u12);
  }
}

// ---------------- final graph reduction ----------------
__global__ void k_final(const float* __restrict__ acc_out, float* __restrict__ out)
{
  __shared__ float red[256];
  int g = blockIdx.x / 9, j = blockIdx.x % 9;
  int tid = threadIdx.x;
  float a = 0.0f;
  for (int n = g*NPG + tid; n < (g + 1)*NPG; n += 256) a += acc_out[n*9 + j];
  red[tid] = a; __syncthreads();
  for (int off = 128; off > 0; off >>= 1) {
    if (tid < off) red[tid] += red[tid + off];
    __syncthreads();
  }
  if (tid == 0) out[g*9 + j] = red[0];
}

extern "C" void kernel_launch(void* const* d_in, const int* in_sizes, int n_in,
                              void* d_out, int out_size, void* d_ws, size_t ws_size,
                              hipStream_t stream)
{
  const float* pos     = (const float*)d_in[0];
  const float* cell    = (const float*)d_in[1];
  const float* Sij     = (const float*)d_in[2];
  const float* W_embed = (const float*)d_in[3];
  const float* W_x     = (const float*)d_in[4];
  const float* W_up_s  = (const float*)d_in[5];
  const float* W_up_v  = (const float*)d_in[6];
  const float* Wr1     = (const float*)d_in[7];
  const float* br1     = (const float*)d_in[8];
  const float* Wr2     = (const float*)d_in[9];
  const float* br2     = (const float*)d_in[10];
  const float* Wr3     = (const float*)d_in[11];
  const float* W_msg_s = (const float*)d_in[12];
  const float* W_msg_v = (const float*)d_in[13];
  const float* W_sc_s  = (const float*)d_in[14];
  const float* W_sc_v  = (const float*)d_in[15];
  const float* W_p_s   = (const float*)d_in[16];
  const float* W_p_v   = (const float*)d_in[17];
  const float* W_read  = (const float*)d_in[18];
  const int*   ei      = (const int*)d_in[19];
  const int*   batch   = (const int*)d_in[20];
  const int*   species = (const int*)d_in[21];
  float* out = (float*)d_out;

  char* ws = (char*)d_ws;
  size_t off = 0;
  auto alloc = [&](size_t bytes) -> void* {
    void* p = ws + off;
    off += (bytes + 255) & ~(size_t)255;
    return p;
  };
  unsigned short* efeatB = (unsigned short*)alloc((size_t)EPAD*8*2);
  float* y1mP    = (float*)alloc((size_t)EPAD*4*4);
  int*   sndP    = (int*)alloc((size_t)EPAD*4);
  unsigned* csrE = (unsigned*)alloc((size_t)EPAD*4);
  float* sF      = (float*)alloc((size_t)NN*64*4);
  float* vF      = (float*)alloc((size_t)NN*192*4);
  float4* nodeP  = (float4*)alloc((size_t)NN*64*16);
  float4* aggP   = (float4*)alloc((size_t)NN*64*16);
  float* acc_out = (float*)alloc((size_t)NN*9*4);
  float* T       = (float*)alloc(512*4);
  float* Tup0    = (float*)alloc(512*4);
  unsigned short* wfrag = (unsigned short*)alloc((size_t)3*WPL*2);
  int* deg     = (int*)alloc((size_t)NN*4);
  int* rowptrP = (int*)alloc((size_t)(NN+1)*4);
  int* cursor  = (int*)alloc((size_t)NN*4);
  int* perm    = (int*)alloc((size_t)NN*4);
  int* hist    = (int*)alloc(8*4);
  int* spcur   = (int*)alloc(8*4);

  hipMemsetAsync(deg, 0, (size_t)NN*4, stream);
  hipMemsetAsync(hist, 0, 8*4, stream);
  hipMemsetAsync(vF, 0, (size_t)NN*192*4, stream);
  hipMemsetAsync(acc_out, 0, (size_t)NN*9*4, stream);
  hipMemsetAsync(csrE, 0xFF, (size_t)EPAD*4, stream);   // pads sort to row tail

  k_count<<<EE/256, 256, 0, stream>>>(ei, deg);
  k_scan <<<1, 1024, 0, stream>>>(deg, rowptrP, cursor);
  k_scatter <<<EE/256, 256, 0, stream>>>(ei, cursor, csrE);
  k_sortrows<<<NN/8, 512, 0, stream>>>(rowptrP, csrE);
  k_geom_slot<<<(EPAD+255)/256, 256, 0, stream>>>(pos, cell, Sij, ei, batch, csrE,
                                                  efeatB, y1mP, sndP);
  k_wprep <<<(3*WPL)/256, 256, 0, stream>>>(Wr1, Wr2, Wr3, wfrag);
  k_spcount<<<(NN+255)/256, 256, 0, stream>>>(species, hist);
  k_spscan<<<1, 64, 0, stream>>>(hist, spcur);
  k_spscatter<<<(NN+255)/256, 256, 0, stream>>>(species, spcur, perm);
  k_tables<<<1, 512, 0, stream>>>(W_embed, W_x, W_up_s, T, Tup0);
  k_embed0<<<NN*64/256, 256, 0, stream>>>(species, W_embed, Tup0, sF, nodeP);

  const int GATHER_BLOCKS = 8 * ((NPG + 7) / 8);   // 2504: graph = b%8 (XCD swizzle)
  for (int l = 0; l < NLAYERS; ++l) {
    k_gather<<<GATHER_BLOCKS, 512, 0, stream>>>(rowptrP, efeatB, (const float4*)y1mP, sndP,
                                                nodeP, wfrag + l*WPL, br1 + l*64, br2 + l*64, aggP);
    int has_next = (l < NLAYERS-1) ? 1 : 0;
    const float* Wus_n = W_up_s + (has_next ? (l+1)*4096 : l*4096);
    const float* Wuv_n = W_up_v + (has_next ? (l+1)*4096 : l*4096);
    k_post<<<NN/16, 512, 0, stream>>>(aggP, species, perm, T, sF, vF,
                                      W_msg_s + l*4096, W_msg_v + l*4096,
                                      W_sc_s + l*32768, W_sc_v + l*32768,
                                      W_p_s + l*4096, W_p_v + l*4096,
                                      W_read + l*192, Wus_n, Wuv_n,
                                      nodeP, acc_out, has_next);
  }
  k_final<<<72, 256, 0, stream>>>(acc_out, out);
}

// Round 12
// 1082.643 us; speedup vs baseline: 1.2413x; 1.2058x over previous
//
#include <hip/hip_runtime.h>
#include <math.h>

#define NN 20000
#define GG 8
#define NPG 2500
#define EE 640000
#define EPAD 944000   // upper bound: E + 15*NN, per-node degree padded to mult of 16
#define NLAYERS 3
#define CUTR 6.0f
#define AVGN 32.0f
#define NBASIS 8
#define WPL 22528     // ushorts of frag-layout weights per layer (Wr1f 2048 + Wr2f 4096 + Wr3f 16384)
#define RTS 88        // shorts per roundtrip row (16B-aligned, breaks 8-way bank conflict of 80)

typedef short bf16x8 __attribute__((ext_vector_type(8)));
typedef float f32x4 __attribute__((ext_vector_type(4)));

__device__ __forceinline__ float silu_f(float x){ return x / (1.0f + __expf(-x)); }
__device__ __forceinline__ unsigned short f2bf(float f){
  union { float f; unsigned u; } x; x.f = f;
  unsigned r = x.u + 0x7FFFu + ((x.u >> 16) & 1u);   // RNE
  return (unsigned short)(r >> 16);
}

// ---------------- CSR degree count ----------------
__global__ void k_count(const int* __restrict__ ei, int* __restrict__ deg)
{
  int e = blockIdx.x * 256 + threadIdx.x;
  if (e >= EE) return;
  atomicAdd(&deg[ei[EE + e]], 1);
}

// padded scan: each row's extent rounded up to multiple of 16 (tiles never cross nodes)
__global__ void k_scan(const int* __restrict__ deg, int* __restrict__ rowptrP,
                       int* __restrict__ cursor)
{
  __shared__ int buf[1024];
  __shared__ int carry;
  int tid = threadIdx.x;
  if (tid == 0) carry = 0;
  __syncthreads();
  for (int base = 0; base < NN; base += 1024) {
    int i = base + tid;
    int x = (i < NN) ? ((deg[i] + 15) & ~15) : 0;
    buf[tid] = x; __syncthreads();
    for (int off = 1; off < 1024; off <<= 1) {
      int t = (tid >= off) ? buf[tid - off] : 0;
      __syncthreads();
      buf[tid] += t;
      __syncthreads();
    }
    int incl = buf[tid];
    int c = carry;
    __syncthreads();
    if (i < NN) { rowptrP[i] = c + incl - x; cursor[i] = c + incl - x; }
    if (tid == 1023) carry = c + incl;
    __syncthreads();
  }
  if (tid == 0) rowptrP[NN] = carry;
}

// ---------------- scatter edge ids into padded CSR slots (perm nondeterministic) ----------------
__global__ void k_scatter(const int* __restrict__ ei, int* __restrict__ cursor,
                          unsigned* __restrict__ csrE)
{
  int e = blockIdx.x * 256 + threadIdx.x;
  if (e >= EE) return;
  int slot = atomicAdd(&cursor[ei[EE + e]], 1);
  csrE[slot] = (unsigned)e;
}

// ---------------- per-row sort by edge id -> DETERMINISTIC slot assignment ----------------
__global__ __launch_bounds__(512) void k_sortrows(const int* __restrict__ rowptrP,
                                                  unsigned* __restrict__ csrE)
{
  __shared__ unsigned buf[8*512];
  int w = threadIdx.x >> 6, lane = threadIdx.x & 63;
  unsigned* b = buf + w*512;
  int r = blockIdx.x*8 + w;
  int start = rowptrP[r], end = rowptrP[r+1];
  int P = end - start;
  if (P < 2 || P > 512) return;   // max padded degree << 512 for this input
  for (int i = lane; i < P; i += 64) b[i] = csrE[start + i];
  for (int pass = 0; pass < P; ++pass) {
    int par = pass & 1;
    for (int i = lane; 2*i + par + 1 < P; i += 64) {
      int idx = 2*i + par;
      unsigned a = b[idx], c = b[idx+1];
      if (a > c) { b[idx] = c; b[idx+1] = a; }
    }
  }
  for (int i = lane; i < P; i += 64) csrE[start + i] = b[i];
}

// ---------------- geometry per SLOT (deterministic values; pads -> zeros) ----------------
__global__ void k_geom_slot(const float* __restrict__ pos, const float* __restrict__ cell,
                            const float* __restrict__ Sij, const int* __restrict__ ei,
                            const int* __restrict__ batch, const unsigned* __restrict__ csrE,
                            unsigned short* __restrict__ efeatB, float* __restrict__ y1mP,
                            int* __restrict__ sndP)
{
  int slot = blockIdx.x * 256 + threadIdx.x;
  if (slot >= EPAD) return;
  int e = (int)csrE[slot];
  if (e < 0) {
    ((uint4*)efeatB)[slot] = make_uint4(0,0,0,0);
    ((float4*)y1mP)[slot]  = make_float4(0,0,0,0);
    sndP[slot] = 0;
    return;
  }
  int snd = ei[e], rcv = ei[EE + e];
  int g = batch[snd];
  float s0 = Sij[e*3+0], s1 = Sij[e*3+1], s2_ = Sij[e*3+2];
  const float* cg = cell + g*9;
  float R[3];
  #pragma unroll
  for (int j = 0; j < 3; ++j) {
    float shift = s0*cg[0*3+j] + s1*cg[1*3+j] + s2_*cg[2*3+j];
    R[j] = (pos[rcv*3+j] - pos[snd*3+j] + shift) * (1.0f/CUTR);
  }
  float len = sqrtf(R[0]*R[0] + R[1]*R[1] + R[2]*R[2]);
  float mk   = (len > 0.0f) ? 1.0f : 0.0f;
  float safe = (len > 0.0f) ? len  : 1.0f;
  float inv  = 1.0f / safe;
  const float sqrt3 = 1.7320508075688772f;
  float x = safe;
  float env = (x < 1.0f) ? (1.0f - 6.0f*x*x + 8.0f*x*x*x - 3.0f*x*x*x*x) : 0.0f;
  float emk = env * mk;
  const float sqrt2 = 1.4142135623730951f;
  const float PI_F = 3.14159265358979323846f;
  union { unsigned short u[8]; uint4 q; } fb;
  #pragma unroll
  for (int n = 1; n <= NBASIS; ++n)
    fb.u[n-1] = f2bf(sqrt2 * __sinf(PI_F * (float)n * safe) * inv * emk);
  ((uint4*)efeatB)[slot] = fb.q;
  ((float4*)y1mP)[slot]  = make_float4(sqrt3*R[0]*inv, sqrt3*R[1]*inv, sqrt3*R[2]*inv, mk);
  sndP[slot] = snd;
}

// ---------------- weight prep: fp32 -> bf16 B-fragment layout for all 3 layers ----------------
// B-frag for 16x16x32: lane L holds B[k=(L>>4)*8+j][n=L&15], j=0..7.
// NOTE (r11 failure): do NOT bake 1/sqrt3 into path-1 weights — bf16(w*c) rounding gets a
// common bias, and h2>0 makes the k=64 dot accumulate it linearly -> absmax 7.3e-3 (fail).
__global__ void k_wprep(const float* __restrict__ Wr1, const float* __restrict__ Wr2,
                        const float* __restrict__ Wr3, unsigned short* __restrict__ wfrag)
{
  int gid = blockIdx.x * 256 + threadIdx.x;
  if (gid >= 3 * WPL) return;
  int l = gid / WPL, r = gid % WPL;
  float val;
  if (r < 2048) {               // Wr1f: 4 frags (ct), K padded 8->32 with zeros
    int f = r >> 9, wi = r & 511, L = wi >> 3, j = wi & 7;
    int k = (L >> 4) * 8 + j, n = L & 15, ct = f;
    val = (k < 8) ? Wr1[l*512 + k*64 + ct*16 + n] : 0.0f;
  } else if (r < 6144) {        // Wr2f: 8 frags (kt*4+ct)
    int r2 = r - 2048;
    int f = r2 >> 9, wi = r2 & 511, L = wi >> 3, j = wi & 7;
    int kt = f >> 2, ct = f & 3;
    int k = kt*32 + (L >> 4)*8 + j, n = L & 15;
    val = Wr2[l*4096 + k*64 + ct*16 + n];
  } else {                      // Wr3f: 32 frags (kt*16+ct), row length 256
    int r3 = r - 6144;
    int f = r3 >> 9, wi = r3 & 511, L = wi >> 3, j = wi & 7;
    int kt = f >> 4, ct = f & 15;
    int k = kt*32 + (L >> 4)*8 + j, n = L & 15;
    val = Wr3[l*16384 + k*256 + ct*16 + n];
  }
  wfrag[gid] = f2bf(val);
}

// ---------------- embed: s, nodeP (layer-0 up), xf table, v/acc_out zero-init ----------------
__global__ void k_embed0(const int* __restrict__ species, const float* __restrict__ W_embed,
                         const float* __restrict__ W_x, const float* __restrict__ Wus0,
                         float* __restrict__ T,
                         float* __restrict__ s, float* __restrict__ v,
                         float4* __restrict__ nodeP, float* __restrict__ acc_out)
{
  if (blockIdx.x == 0) {        // xf table (512 entries), used by k_post every layer
    for (int t = threadIdx.x; t < 512; t += 256) {
      int sp = t >> 6, o = t & 63;
      float a = 0.0f;
      for (int k = 0; k < 64; ++k) a += W_embed[sp*64 + k] * W_x[k*64 + o];
      T[t] = a;
    }
  }
  int gid = blockIdx.x * 256 + threadIdx.x;
  if (gid >= NN * 64) return;
  int n = gid >> 6, c = gid & 63;
  int sp = species[n];
  s[gid] = W_embed[sp*64 + c];
  float up = 0.0f;              // layer-0 s_up inline (v=0 so v_up=0)
  for (int k = 0; k < 64; ++k) up += W_embed[sp*64 + k] * Wus0[k*64 + c];
  nodeP[gid] = make_float4(up, 0.0f, 0.0f, 0.0f);
  #pragma unroll
  for (int m = 0; m < 3; ++m) v[(n*3 + m)*64 + c] = 0.0f;
  if (c < 9) acc_out[n*9 + c] = 0.0f;
}

// ---------------- gather: MFMA radial MLP + messages + aggregation ----------------
// (512,2) = 256-reg wave, whole-tile np prefetch, sched_barrier per ctm: zero spill (r8:
// WRITE 69 MB). (512,3) re-spilled (r9: WRITE 211 MB) — do not raise occupancy here.
// XCD swizzle: block b -> graph b%8; one graph's nodeP (2.5 MB) lives in that XCD's L2.
// Edge mask folded into the h2 roundtrip write (mask∈{0,1} -> bitwise exact).
// A-layout: A[m=lane&15][k=quad*8+j]; C/D: col=lane&15, row=quad*4+reg (m89/m120 verified).
__global__ __launch_bounds__(512, 2) void k_gather(
    const int* __restrict__ rowptrP,
    const unsigned short* __restrict__ efeatB, const float4* __restrict__ y1mP,
    const int* __restrict__ sndP, const float4* __restrict__ nodeP,
    const unsigned short* __restrict__ wfrag,
    const float* __restrict__ br1, const float* __restrict__ br2,
    float4* __restrict__ aggP)
{
  __shared__ unsigned short smw[WPL];          // 45056 B: Wr1f | Wr2f | Wr3f
  __shared__ float smf[128];                   // br1 | br2
  __shared__ unsigned short rtAll[8*16*RTS];   // 22528 B: per-wave MFMA roundtrip
  __shared__ float4 ymAll[8*16];               // 2048 B: per-wave y1m tile
  __shared__ int sndAll[8*16];                 // 512 B: per-wave snd tile
  int tid = threadIdx.x;
  if (tid < 64) { smf[tid] = br1[tid]; smf[64+tid] = br2[tid]; }
  {
    const unsigned* src = (const unsigned*)wfrag;
    unsigned* dst = (unsigned*)smw;
    for (int i = tid; i < WPL/2; i += 512) dst[i] = src[i];
  }
  __syncthreads();
  const unsigned short* Wr1f = smw;
  const unsigned short* Wr2f = smw + 2048;
  const unsigned short* Wr3f = smw + 6144;

  int w = tid >> 6, lane = tid & 63;
  int n16 = lane & 15, quad = lane >> 4;
  unsigned short* rt = rtAll + w*16*RTS;
  float4* ym = ymAll + w*16;
  int* sndL = sndAll + w*16;
  // XCD swizzle: graph = blockIdx%8, node-within-graph = (blockIdx/8)*8 + wave
  int g = blockIdx.x & 7, rr = (blockIdx.x >> 3)*8 + w;
  if (rr < NPG) {
  int r = g*NPG + rr;
  int start = rowptrP[r], end = rowptrP[r+1];
  float as[4] = {0,0,0,0};
  float av[4][3] = {{0,0,0},{0,0,0},{0,0,0},{0,0,0}};
  const float inv_sqrt3 = 0.5773502691896258f;

  for (int e0 = start; e0 < end; e0 += 16) {
    // stage edge meta in per-wave LDS (in-wave lockstep; DS ops are in-order per wave)
    if (quad == 1) ym[n16] = y1mP[e0 + n16];
    if (quad == 2) sndL[n16] = sndP[e0 + n16];
    // prefetch sender rows for the whole tile (issued early; h1/h2 MFMAs hide latency)
    float4 np[4][4];
    #pragma unroll
    for (int ctm = 0; ctm < 4; ++ctm)
      #pragma unroll
      for (int j = 0; j < 4; ++j)
        np[ctm][j] = nodeP[(size_t)sndL[quad*4 + j]*64 + ctm*16 + n16];
    // efeat A-frag: quad0 = k 0..7 (real), quads 1-3 = k 8..31 (zero; Wr1f zero-padded too)
    bf16x8 aef = (bf16x8){0,0,0,0,0,0,0,0};
    if (quad == 0)
      aef = *(const bf16x8*)(efeatB + (size_t)(e0 + n16)*8);
    // ---- h1 = silu(efeat @ Wr1 + b1): 4 MFMAs ----
    f32x4 hacc[4];
    #pragma unroll
    for (int ct = 0; ct < 4; ++ct) {
      bf16x8 bf = *(const bf16x8*)(Wr1f + (ct*64 + lane)*8);
      hacc[ct] = __builtin_amdgcn_mfma_f32_16x16x32_bf16(aef, bf, (f32x4){0,0,0,0}, 0, 0, 0);
    }
    #pragma unroll
    for (int ct = 0; ct < 4; ++ct) {
      int ch = ct*16 + n16;
      float b = smf[ch];
      #pragma unroll
      for (int reg = 0; reg < 4; ++reg)
        rt[(quad*4 + reg)*RTS + ch] = f2bf(silu_f(hacc[ct][reg] + b));
    }
    bf16x8 a1[2];    // wave-lockstep LDS roundtrip (per-wave buffer, no barrier)
    #pragma unroll
    for (int kt = 0; kt < 2; ++kt)
      a1[kt] = *(const bf16x8*)(rt + n16*RTS + kt*32 + quad*8);
    // ---- h2 = silu(h1 @ Wr2 + b2): 8 MFMAs; edge mask folded into the write ----
    #pragma unroll
    for (int ct = 0; ct < 4; ++ct) {
      bf16x8 b0 = *(const bf16x8*)(Wr2f + ((0*4 + ct)*64 + lane)*8);
      bf16x8 b1 = *(const bf16x8*)(Wr2f + ((1*4 + ct)*64 + lane)*8);
      f32x4 acc = __builtin_amdgcn_mfma_f32_16x16x32_bf16(a1[0], b0, (f32x4){0,0,0,0}, 0, 0, 0);
      hacc[ct]  = __builtin_amdgcn_mfma_f32_16x16x32_bf16(a1[1], b1, acc, 0, 0, 0);
    }
    #pragma unroll
    for (int ct = 0; ct < 4; ++ct) {
      int ch = ct*16 + n16;
      float b = smf[64 + ch];
      #pragma unroll
      for (int reg = 0; reg < 4; ++reg) {
        float mkr = ym[quad*4 + reg].w;   // mask of this C-row's edge (0 or 1 -> exact)
        rt[(quad*4 + reg)*RTS + ch] = f2bf(silu_f(hacc[ct][reg] + b) * mkr);
      }
    }
    bf16x8 a2[2];
    #pragma unroll
    for (int kt = 0; kt < 2; ++kt)
      a2[kt] = *(const bf16x8*)(rt + n16*RTS + kt*32 + quad*8);
    // ---- wts = h2 @ Wr3 per channel-group; message paths fused ----
    #pragma unroll
    for (int ctm = 0; ctm < 4; ++ctm) {
      f32x4 wacc[4];
      #pragma unroll
      for (int p = 0; p < 4; ++p) {
        int ct = p*4 + ctm;      // path p, channels ctm*16..+15
        f32x4 acc = __builtin_amdgcn_mfma_f32_16x16x32_bf16(
            a2[0], *(const bf16x8*)(Wr3f + ((0*16 + ct)*64 + lane)*8), (f32x4){0,0,0,0}, 0, 0, 0);
        wacc[p] = __builtin_amdgcn_mfma_f32_16x16x32_bf16(
            a2[1], *(const bf16x8*)(Wr3f + ((1*16 + ct)*64 + lane)*8), acc, 0, 0, 0);
      }
      #pragma unroll
      for (int j = 0; j < 4; ++j) {   // C row = quad*4+j = edge e0+quad*4+j
        float4 y = ym[quad*4 + j];    // broadcast LDS read
        float4 npv = np[ctm][j];
        float dot = npv.y*y.x + npv.z*y.y + npv.w*y.z;
        float t2 = wacc[2][j]*npv.x;
        as[ctm]    += wacc[0][j]*npv.x + wacc[1][j]*dot*inv_sqrt3;
        av[ctm][0] += t2*y.x + wacc[3][j]*npv.y;
        av[ctm][1] += t2*y.y + wacc[3][j]*npv.z;
        av[ctm][2] += t2*y.z + wacc[3][j]*npv.w;
      }
      __builtin_amdgcn_sched_barrier(0);   // keep ctm iterations from interleaving (reg cap)
    }
  }
  // cross-quad butterfly + write packed agg
  const float invavg = 1.0f / AVGN;
  #pragma unroll
  for (int ctm = 0; ctm < 4; ++ctm) {
    float v0 = as[ctm], v1 = av[ctm][0], v2 = av[ctm][1], v3 = av[ctm][2];
    v0 += __shfl_xor(v0, 16); v0 += __shfl_xor(v0, 32);
    v1 += __shfl_xor(v1, 16); v1 += __shfl_xor(v1, 32);
    v2 += __shfl_xor(v2, 16); v2 += __shfl_xor(v2, 32);
    v3 += __shfl_xor(v3, 16); v3 += __shfl_xor(v3, 32);
    if (quad == 0)
      aggP[(size_t)r*64 + ctm*16 + n16] =
          make_float4(v0*invavg, v1*invavg, v2*invavg, v3*invavg);
  }
  }  // rr < NPG
}

// ---------------- post: msg/sc/product + readout + NEXT layer's up-projection ----------------
// Round-8 exact: 1 node/wave, 32 KB LDS -> 4 blocks/CU (32 waves). L2-streamed weights.
// r9 (96 KB LDS stage, 8 waves) and r10 (2 nodes/wave, 16 waves) both lost more to
// occupancy than they gained in traffic — keep occupancy.
__global__ __launch_bounds__(512) void k_post(
    const float4* __restrict__ aggP, const int* __restrict__ species,
    const float* __restrict__ T,
    float* __restrict__ s, float* __restrict__ v,
    const float* __restrict__ Wms, const float* __restrict__ Wmv,
    const float* __restrict__ Wscs, const float* __restrict__ Wscv,
    const float* __restrict__ Wps, const float* __restrict__ Wpv,
    const float* __restrict__ Wread,
    const float* __restrict__ Wus_n, const float* __restrict__ Wuv_n,
    float4* __restrict__ nodeP, float* __restrict__ acc_out, int has_next)
{
  __shared__ float lds[8*1024];
  int tid = threadIdx.x; int w = tid >> 6, c = tid & 63;
  float* asb = lds + w*1024;   // 64
  float* avb = asb + 64;       // 192
  float* sob = avb + 192;      // 64
  float* vob = sob + 64;       // 192
  float* tsb = vob + 192;      // 64
  float* tvb = tsb + 64;       // 192
  float* snb = tvb + 192;      // 64
  float* vnb = snb + 64;       // 192
  int n = blockIdx.x*8 + w;
  int sp = species[n];
  float4 ag = aggP[(size_t)n*64 + c];
  asb[c] = ag.x; avb[c] = ag.y; avb[64+c] = ag.z; avb[128+c] = ag.w;
  sob[c] = s[n*64 + c];
  #pragma unroll
  for (int m = 0; m < 3; ++m) vob[m*64 + c] = v[(n*3 + m)*64 + c];
  // wave-lockstep LDS (per-wave region, no barrier)
  float ms = 0, mv0 = 0, mv1 = 0, mv2 = 0;
  for (int k = 0; k < 64; ++k) {
    float wm = Wms[k*64 + c];
    ms  += asb[k]*wm;
    float wv = Wmv[k*64 + c];
    mv0 += avb[k]*wv; mv1 += avb[64+k]*wv; mv2 += avb[128+k]*wv;
  }
  float xf = T[sp*64 + c];
  tsb[c] = xf*ms; tvb[c] = xf*mv0; tvb[64+c] = xf*mv1; tvb[128+c] = xf*mv2;
  const float* Wss = Wscs + sp*4096;
  const float* Wsv = Wscv + sp*4096;
  float sn_ = 0, vn0 = 0, vn1 = 0, vn2 = 0;
  for (int k = 0; k < 64; ++k) {
    float wp  = Wps[k*64 + c];  sn_ += tsb[k]*wp;
    float wsc = Wss[k*64 + c];  sn_ += sob[k]*wsc;
    float wpv = Wpv[k*64 + c];
    vn0 += tvb[k]*wpv; vn1 += tvb[64+k]*wpv; vn2 += tvb[128+k]*wpv;
    float wsv = Wsv[k*64 + c];
    vn0 += vob[k]*wsv; vn1 += vob[64+k]*wsv; vn2 += vob[128+k]*wsv;
  }
  s[n*64 + c] = sn_;
  v[(n*3+0)*64 + c] = vn0; v[(n*3+1)*64 + c] = vn1; v[(n*3+2)*64 + c] = vn2;
  snb[c] = sn_; vnb[c] = vn0; vnb[64+c] = vn1; vnb[128+c] = vn2;
  if (c < 9) {                         // readout, silu-accumulated across layers
    int o3 = c / 3, m = c % 3;
    const float* wr = Wread + o3*64;
    float a = 0.0f;
    for (int k = 0; k < 64; ++k) a += vnb[m*64 + k]*wr[k];
    acc_out[n*9 + c] += silu_f(a);
  }
  if (has_next) {                      // fused up-projection for next layer
    float su = 0, u0 = 0, u1 = 0, u2 = 0;
    for (int k = 0; k < 64; ++k) {
      float wu = Wus_n[k*64 + c]; su += snb[k]*wu;
      float wv = Wuv_n[k*64 + c];
      u0 += vnb[k]*wv; u1 += vnb[64+k]*wv; u2 += vnb[128+k]*wv;
    }
    nodeP[(size_t)n*64 + c] = make_float4(su, u0, u1, u2);
  }
}

// ---------------- final graph reduction ----------------
__global__ void k_final(const float* __restrict__ acc_out, float* __restrict__ out)
{
  __shared__ float red[256];
  int g = blockIdx.x / 9, j = blockIdx.x % 9;
  int tid = threadIdx.x;
  float a = 0.0f;
  for (int n = g*NPG + tid; n < (g + 1)*NPG; n += 256) a += acc_out[n*9 + j];
  red[tid] = a; __syncthreads();
  for (int off = 128; off > 0; off >>= 1) {
    if (tid < off) red[tid] += red[tid + off];
    __syncthreads();
  }
  if (tid == 0) out[g*9 + j] = red[0];
}

extern "C" void kernel_launch(void* const* d_in, const int* in_sizes, int n_in,
                              void* d_out, int out_size, void* d_ws, size_t ws_size,
                              hipStream_t stream)
{
  const float* pos     = (const float*)d_in[0];
  const float* cell    = (const float*)d_in[1];
  const float* Sij     = (const float*)d_in[2];
  const float* W_embed = (const float*)d_in[3];
  const float* W_x     = (const float*)d_in[4];
  const float* W_up_s  = (const float*)d_in[5];
  const float* W_up_v  = (const float*)d_in[6];
  const float* Wr1     = (const float*)d_in[7];
  const float* br1     = (const float*)d_in[8];
  const float* Wr2     = (const float*)d_in[9];
  const float* br2     = (const float*)d_in[10];
  const float* Wr3     = (const float*)d_in[11];
  const float* W_msg_s = (const float*)d_in[12];
  const float* W_msg_v = (const float*)d_in[13];
  const float* W_sc_s  = (const float*)d_in[14];
  const float* W_sc_v  = (const float*)d_in[15];
  const float* W_p_s   = (const float*)d_in[16];
  const float* W_p_v   = (const float*)d_in[17];
  const float* W_read  = (const float*)d_in[18];
  const int*   ei      = (const int*)d_in[19];
  const int*   batch   = (const int*)d_in[20];
  const int*   species = (const int*)d_in[21];
  float* out = (float*)d_out;

  char* ws = (char*)d_ws;
  size_t off = 0;
  auto alloc = [&](size_t bytes) -> void* {
    void* p = ws + off;
    off += (bytes + 255) & ~(size_t)255;
    return p;
  };
  unsigned short* efeatB = (unsigned short*)alloc((size_t)EPAD*8*2);
  float* y1mP    = (float*)alloc((size_t)EPAD*4*4);
  int*   sndP    = (int*)alloc((size_t)EPAD*4);
  unsigned* csrE = (unsigned*)alloc((size_t)EPAD*4);
  float* sF      = (float*)alloc((size_t)NN*64*4);
  float* vF      = (float*)alloc((size_t)NN*192*4);
  float4* nodeP  = (float4*)alloc((size_t)NN*64*16);
  float4* aggP   = (float4*)alloc((size_t)NN*64*16);
  float* acc_out = (float*)alloc((size_t)NN*9*4);
  float* T       = (float*)alloc(512*4);
  unsigned short* wfrag = (unsigned short*)alloc((size_t)3*WPL*2);
  int* deg     = (int*)alloc((size_t)NN*4);
  int* rowptrP = (int*)alloc((size_t)(NN+1)*4);
  int* cursor  = (int*)alloc((size_t)NN*4);

  hipMemsetAsync(deg, 0, (size_t)NN*4, stream);
  hipMemsetAsync(csrE, 0xFF, (size_t)EPAD*4, stream);   // pads sort to row tail

  k_count<<<EE/256, 256, 0, stream>>>(ei, deg);
  k_scan <<<1, 1024, 0, stream>>>(deg, rowptrP, cursor);
  k_scatter <<<EE/256, 256, 0, stream>>>(ei, cursor, csrE);
  k_sortrows<<<NN/8, 512, 0, stream>>>(rowptrP, csrE);
  k_geom_slot<<<(EPAD+255)/256, 256, 0, stream>>>(pos, cell, Sij, ei, batch, csrE,
                                                  efeatB, y1mP, sndP);
  k_wprep <<<(3*WPL)/256, 256, 0, stream>>>(Wr1, Wr2, Wr3, wfrag);
  k_embed0<<<NN*64/256, 256, 0, stream>>>(species, W_embed, W_x, W_up_s, T,
                                          sF, vF, nodeP, acc_out);

  const int GATHER_BLOCKS = 8 * ((NPG + 7) / 8);   // 2504: graph = b%8 (XCD swizzle)
  for (int l = 0; l < NLAYERS; ++l) {
    k_gather<<<GATHER_BLOCKS, 512, 0, stream>>>(rowptrP, efeatB, (const float4*)y1mP, sndP,
                                                nodeP, wfrag + l*WPL, br1 + l*64, br2 + l*64, aggP);
    int has_next = (l < NLAYERS-1) ? 1 : 0;
    const float* Wus_n = W_up_s + (has_next ? (l+1)*4096 : l*4096);
    const float* Wuv_n = W_up_v + (has_next ? (l+1)*4096 : l*4096);
    k_post<<<2500, 512, 0, stream>>>(aggP, species, T, sF, vF,
                                     W_msg_s + l*4096, W_msg_v + l*4096,
                                     W_sc_s + l*32768, W_sc_v + l*32768,
                                     W_p_s + l*4096, W_p_v + l*4096,
                                     W_read + l*192, Wus_n, Wuv_n,
                                     nodeP, acc_out, has_next);
  }
  k_final<<<72, 256, 0, stream>>>(acc_out, out);
}